// Round 3
// baseline (684.906 us; speedup 1.0000x reference)
//
#include <hip/hip_runtime.h>
#include <stdint.h>

// SymmetricContraction (MACE) on MI355X, fp32 I/O.
// R3: (1) NT=4 nodes/lane with (m,j)-space split across waves -> 4x fewer
// LDS row reads; (2) LDS layout [m][j][i][l] so build writes are stride-1
// (conflict-free); (3) node-list compaction hoisted to a prep kernel (d_ws).

#define BN 2048
#define CN 128
#define EN 10

// ---------- prep: per-element node lists into ws ----------
// ws layout: counts = int[16] at 0; lists = int[EN][BN] after.
__global__ void compact_kernel(const float* __restrict__ yg, int* __restrict__ ws) {
    __shared__ int cnt_s[EN];
    const int tid = threadIdx.x;
    if (tid < EN) cnt_s[tid] = 0;
    __syncthreads();
    int* lists = ws + 16;
    for (int b = tid; b < BN; b += 256) {
#pragma unroll
        for (int e = 0; e < EN; ++e) {
            if (yg[b * EN + e] > 0.5f) {
                int p = atomicAdd(&cnt_s[e], 1);
                lists[e * BN + p] = b;
                break;
            }
        }
    }
    __syncthreads();
    if (tid < EN) ws[tid] = cnt_s[tid];
}

__device__ __forceinline__ float dot16(const float4 r0, const float4 r1,
                                       const float4 r2, const float4 r3,
                                       const float* x) {
    float a = r0.x * x[0];
    a = fmaf(r0.y, x[1], a);
    a = fmaf(r0.z, x[2], a);
    a = fmaf(r0.w, x[3], a);
    a = fmaf(r1.x, x[4], a);
    a = fmaf(r1.y, x[5], a);
    a = fmaf(r1.z, x[6], a);
    a = fmaf(r1.w, x[7], a);
    a = fmaf(r2.x, x[8], a);
    a = fmaf(r2.y, x[9], a);
    a = fmaf(r2.z, x[10], a);
    a = fmaf(r2.w, x[11], a);
    a = fmaf(r3.x, x[12], a);
    a = fmaf(r3.y, x[13], a);
    a = fmaf(r3.z, x[14], a);
    a = fmaf(r3.w, x[15], a);
    return a;
}

template <int M, int K3, int K2, int OUTBASE>
__global__ __launch_bounds__(256, 3) void sc_main(
    const float* __restrict__ xg,   // [B, C, 16]
    const float* __restrict__ U3,   // [M,16,16,16,K3] (m,i,j,l,k)
    const float* __restrict__ U2,   // [M,16,16,K2]    (m,j,l,k)
    const float* __restrict__ U1,   // [M,16,1]
    const float* __restrict__ W3, const float* __restrict__ W2,
    const float* __restrict__ W1,
    const int* __restrict__ ws,     // counts + lists
    float* __restrict__ outg)       // [B, 512]
{
    const int c = blockIdx.x;
    const int e = blockIdx.y;
    const int tid = threadIdx.x;
    const int lane = tid & 63;
    const int wave = tid >> 6;

    __shared__ float c3s[M * 4096];   // [m][j][i][l]
    __shared__ float c2s[M * 256];    // [m][j][l]
    __shared__ float c1s[M * 16];
    __shared__ float wk3s[K3];
    __shared__ float wk2s[K2];
    __shared__ float wk1s[1];
    __shared__ float red4[(M == 1) ? 4 * 256 : 1];

    if (tid < K3) wk3s[tid] = W3[(e * K3 + tid) * CN + c];
    if (tid >= 64 && tid < 64 + K2) wk2s[tid - 64] = W2[(e * K2 + (tid - 64)) * CN + c];
    if (tid == 96) wk1s[0] = W1[e * CN + c];
    __syncthreads();

    // --- build tables. idx enumerates U3 linear order (m,i,j,l); LDS write
    // goes to [m][j][i][l] so lanes (varying l) write stride-1: conflict-free.
    for (int idx = tid; idx < M * 4096; idx += 256) {
        const int l = idx & 15;
        const int j = (idx >> 4) & 15;
        const int i = (idx >> 8) & 15;
        const int m = idx >> 12;
        const float* up = U3 + (size_t)idx * K3;
        float acc = 0.f;
#pragma unroll
        for (int k = 0; k < K3; ++k) acc = fmaf(up[k], wk3s[k], acc);
        c3s[((m * 16 + j) * 16 + i) * 16 + l] = acc;
    }
    for (int idx = tid; idx < M * 256; idx += 256) {
        const float* up = U2 + (size_t)idx * K2;
        float acc = 0.f;
#pragma unroll
        for (int k = 0; k < K2; ++k) acc = fmaf(up[k], wk2s[k], acc);
        c2s[idx] = acc;
    }
    if (tid < M * 16) c1s[tid] = U1[tid] * wk1s[0];
    __syncthreads();

    const int cnt = ws[e];
    const int* list = ws + 16 + e * BN;

    for (int base = 0; base < cnt; base += 256) {
        // each lane carries NT=4 nodes
        int nn[4];
        float xr[4][16];
#pragma unroll
        for (int t = 0; t < 4; ++t) {
            const int slot = base + t * 64 + lane;
            nn[t] = (slot < cnt) ? list[slot] : -1;
            const int nsafe = (nn[t] < 0) ? 0 : nn[t];
            const float4* xp = (const float4*)(xg + ((size_t)nsafe * CN + c) * 16);
            const float4 a0 = xp[0], a1 = xp[1], a2 = xp[2], a3 = xp[3];
            xr[t][0] = a0.x; xr[t][1] = a0.y; xr[t][2] = a0.z; xr[t][3] = a0.w;
            xr[t][4] = a1.x; xr[t][5] = a1.y; xr[t][6] = a1.z; xr[t][7] = a1.w;
            xr[t][8] = a2.x; xr[t][9] = a2.y; xr[t][10] = a2.z; xr[t][11] = a2.w;
            xr[t][12] = a3.x; xr[t][13] = a3.y; xr[t][14] = a3.z; xr[t][15] = a3.w;
        }

        if constexpr (M == 1) {
            // ---- part0: 4-way j-split + LDS reduction ----
            float fmp[4] = {0.f, 0.f, 0.f, 0.f};
#pragma unroll 1
            for (int jj = 0; jj < 4; ++jj) {
                const int j = wave * 4 + jj;  // mj == j
                const float4* c2r = (const float4*)(c2s + j * 16);
                const float4 q0 = c2r[0], q1 = c2r[1], q2 = c2r[2], q3 = c2r[3];
                float bj[4];
#pragma unroll
                for (int t = 0; t < 4; ++t) bj[t] = dot16(q0, q1, q2, q3, xr[t]);
#pragma unroll 4
                for (int i = 0; i < 16; ++i) {
                    const float4* row = (const float4*)(c3s + (j * 16 + i) * 16);
                    const float4 r0 = row[0], r1 = row[1], r2 = row[2], r3 = row[3];
#pragma unroll
                    for (int t = 0; t < 4; ++t) {
                        const float s = dot16(r0, r1, r2, r3, xr[t]);
                        bj[t] = fmaf(xr[t][i], s, bj[t]);
                    }
                }
                const float c1v = c1s[j];
#pragma unroll
                for (int t = 0; t < 4; ++t) {
                    const int nsafe = (nn[t] < 0) ? 0 : nn[t];
                    const float xj = xg[((size_t)nsafe * CN + c) * 16 + j];
                    fmp[t] = fmaf(bj[t] + c1v, xj, fmp[t]);
                }
            }
            __syncthreads();  // red4 free from previous pass
#pragma unroll
            for (int t = 0; t < 4; ++t) red4[wave * 256 + t * 64 + lane] = fmp[t];
            __syncthreads();
            {
                const int slot = base + tid;
                if (slot < cnt) {
                    const float s = red4[tid] + red4[256 + tid] + red4[512 + tid] + red4[768 + tid];
                    const int n = list[slot];
                    outg[(size_t)n * 512 + OUTBASE + c] = s;
                }
            }
        } else {
            // ---- part1: wave w (<M) owns m = w, all 16 j, direct store ----
            if (wave < M) {
                const int m = wave;
                float fm[4] = {0.f, 0.f, 0.f, 0.f};
#pragma unroll 1
                for (int j = 0; j < 16; ++j) {
                    const int mj = m * 16 + j;
                    const float4* c2r = (const float4*)(c2s + mj * 16);
                    const float4 q0 = c2r[0], q1 = c2r[1], q2 = c2r[2], q3 = c2r[3];
                    float bj[4];
#pragma unroll
                    for (int t = 0; t < 4; ++t) bj[t] = dot16(q0, q1, q2, q3, xr[t]);
#pragma unroll 4
                    for (int i = 0; i < 16; ++i) {
                        const float4* row = (const float4*)(c3s + (mj * 16 + i) * 16);
                        const float4 r0 = row[0], r1 = row[1], r2 = row[2], r3 = row[3];
#pragma unroll
                        for (int t = 0; t < 4; ++t) {
                            const float s = dot16(r0, r1, r2, r3, xr[t]);
                            bj[t] = fmaf(xr[t][i], s, bj[t]);
                        }
                    }
                    const float c1v = c1s[mj];
#pragma unroll
                    for (int t = 0; t < 4; ++t) {
                        const int nsafe = (nn[t] < 0) ? 0 : nn[t];
                        const float xj = xg[((size_t)nsafe * CN + c) * 16 + j];
                        fm[t] = fmaf(bj[t] + c1v, xj, fm[t]);
                    }
                }
#pragma unroll
                for (int t = 0; t < 4; ++t) {
                    if (nn[t] >= 0)
                        outg[(size_t)nn[t] * 512 + OUTBASE + c * M + m] = fm[t];
                }
            }
        }
    }
}

extern "C" void kernel_launch(void* const* d_in, const int* in_sizes, int n_in,
                              void* d_out, int out_size, void* d_ws, size_t ws_size,
                              hipStream_t stream) {
    const float* x = (const float*)d_in[0];
    const float* y = (const float*)d_in[1];
    const float* U3_0 = (const float*)d_in[2];
    const float* U2_0 = (const float*)d_in[3];
    const float* U1_0 = (const float*)d_in[4];
    const float* W3_0 = (const float*)d_in[5];
    const float* W2_0 = (const float*)d_in[6];
    const float* W1_0 = (const float*)d_in[7];
    const float* U3_1 = (const float*)d_in[8];
    const float* U2_1 = (const float*)d_in[9];
    const float* U1_1 = (const float*)d_in[10];
    const float* W3_1 = (const float*)d_in[11];
    const float* W2_1 = (const float*)d_in[12];
    const float* W1_1 = (const float*)d_in[13];
    float* out = (float*)d_out;
    int* ws = (int*)d_ws;

    compact_kernel<<<1, 256, 0, stream>>>(y, ws);

    dim3 grid(CN, EN);
    sc_main<1, 23, 4, 0><<<grid, 256, 0, stream>>>(x, U3_0, U2_0, U1_0, W3_0, W2_0, W1_0, ws, out);
    sc_main<3, 33, 5, 128><<<grid, 256, 0, stream>>>(x, U3_1, U2_1, U1_1, W3_1, W2_1, W1_1, ws, out);
}

// Round 4
// 682.846 us; speedup vs baseline: 1.0030x; 1.0030x over previous
//
#include <hip/hip_runtime.h>
#include <stdint.h>

// SymmetricContraction (MACE) on MI355X, fp32 I/O.
// R4: grid = (c, e, m). Per block: build 16KB m-slice table c3[j][i][l] in LDS
// (stride-1 writes), stage this block's node x-vectors in LDS transposed
// xs[i][slot] (each node's x fetched from global exactly once per block),
// 4-way j-split across waves with NT=4 nodes/lane, LDS cross-wave reduction
// (aliased over xs), one dword store per node.

#define BN 2048
#define CN 128
#define EN 10

// ws layout: counts int[16]; lists int[EN][BN].
__global__ void compact_kernel(const float* __restrict__ yg, int* __restrict__ ws) {
    __shared__ int cnt_s[EN];
    const int tid = threadIdx.x;
    if (tid < EN) cnt_s[tid] = 0;
    __syncthreads();
    int* lists = ws + 16;
    for (int b = tid; b < BN; b += 256) {
#pragma unroll
        for (int e = 0; e < EN; ++e) {
            if (yg[b * EN + e] > 0.5f) {
                int p = atomicAdd(&cnt_s[e], 1);
                lists[e * BN + p] = b;
                break;
            }
        }
    }
    __syncthreads();
    if (tid < EN) ws[tid] = cnt_s[tid];
}

__device__ __forceinline__ float dot16(const float4 r0, const float4 r1,
                                       const float4 r2, const float4 r3,
                                       const float* x) {
    float a = r0.x * x[0];
    a = fmaf(r0.y, x[1], a);
    a = fmaf(r0.z, x[2], a);
    a = fmaf(r0.w, x[3], a);
    a = fmaf(r1.x, x[4], a);
    a = fmaf(r1.y, x[5], a);
    a = fmaf(r1.z, x[6], a);
    a = fmaf(r1.w, x[7], a);
    a = fmaf(r2.x, x[8], a);
    a = fmaf(r2.y, x[9], a);
    a = fmaf(r2.z, x[10], a);
    a = fmaf(r2.w, x[11], a);
    a = fmaf(r3.x, x[12], a);
    a = fmaf(r3.y, x[13], a);
    a = fmaf(r3.z, x[14], a);
    a = fmaf(r3.w, x[15], a);
    return a;
}

template <int K3, int K2, int CM, int OUTBASE>
__global__ __launch_bounds__(256, 4) void sc_main(
    const float* __restrict__ xg,   // [B, C, 16]
    const float* __restrict__ U3,   // [M,16,16,16,K3] (m,i,j,l,k)
    const float* __restrict__ U2,   // [M,16,16,K2]
    const float* __restrict__ U1,   // [M,16,1]
    const float* __restrict__ W3, const float* __restrict__ W2,
    const float* __restrict__ W1,
    const int* __restrict__ ws,
    float* __restrict__ outg)       // [B, 512]
{
    const int c = blockIdx.x;
    const int e = blockIdx.y;
    const int m = blockIdx.z;
    const int tid = threadIdx.x;
    const int lane = tid & 63;
    const int wave = tid >> 6;

    __shared__ float c3s[4096];      // [j][i][l]
    __shared__ float c2s[256];       // [j][l]
    __shared__ float c1s[16];
    __shared__ float wk3s[K3];
    __shared__ float wk2s[K2 + 1];   // [K2] holds w1
    __shared__ float xs[16 * 256];   // [i][slot]; first 1024 aliased as red[4][256]

    if (tid < K3) wk3s[tid] = W3[(e * K3 + tid) * CN + c];
    if (tid >= 64 && tid < 64 + K2) wk2s[tid - 64] = W2[(e * K2 + (tid - 64)) * CN + c];
    if (tid == 96) wk2s[K2] = W1[e * CN + c];
    __syncthreads();

    // build c3 m-slice: idx enumerates LDS order [j][i][l]; gather from U3
    const float* U3m = U3 + (size_t)m * 4096 * K3;
    for (int idx = tid; idx < 4096; idx += 256) {
        const int l = idx & 15;
        const int i = (idx >> 4) & 15;
        const int j = idx >> 8;
        const float* up = U3m + ((size_t)((i * 16 + j) * 16 + l)) * K3;
        float acc = 0.f;
#pragma unroll
        for (int k = 0; k < K3; ++k) acc = fmaf(up[k], wk3s[k], acc);
        c3s[idx] = acc;  // stride-1 write: conflict-free
    }
    {
        // c2: U2 m-slice linear (j,l,k) matches LDS [j][l]
        const float* up = U2 + ((size_t)m * 256 + tid) * K2;
        float acc = 0.f;
#pragma unroll
        for (int k = 0; k < K2; ++k) acc = fmaf(up[k], wk2s[k], acc);
        c2s[tid] = acc;
    }
    if (tid < 16) c1s[tid] = U1[m * 16 + tid] * wk2s[K2];
    __syncthreads();

    const int cnt = ws[e];
    const int* list = ws + 16 + e * BN;

    for (int base = 0; base < cnt; base += 256) {
        // ---- stage x for up to 256 nodes, transposed ----
        {
            const int slot = base + tid;
            const int n = (slot < cnt) ? list[slot] : list[cnt - 1];
            const float4* xp = (const float4*)(xg + ((size_t)n * CN + c) * 16);
            const float4 a0 = xp[0], a1 = xp[1], a2 = xp[2], a3 = xp[3];
            float v[16];
            v[0] = a0.x; v[1] = a0.y; v[2] = a0.z; v[3] = a0.w;
            v[4] = a1.x; v[5] = a1.y; v[6] = a1.z; v[7] = a1.w;
            v[8] = a2.x; v[9] = a2.y; v[10] = a2.z; v[11] = a2.w;
            v[12] = a3.x; v[13] = a3.y; v[14] = a3.z; v[15] = a3.w;
#pragma unroll
            for (int i = 0; i < 16; ++i) xs[i * 256 + tid] = v[i];  // lanes stride-1
        }
        __syncthreads();

        // ---- per-lane registers for 4 nodes ----
        float xr[4][16];
#pragma unroll
        for (int t = 0; t < 4; ++t)
#pragma unroll
            for (int i = 0; i < 16; ++i) xr[t][i] = xs[i * 256 + t * 64 + lane];

        float fmp[4] = {0.f, 0.f, 0.f, 0.f};
#pragma unroll 1
        for (int jj = 0; jj < 4; ++jj) {
            const int j = wave * 4 + jj;
            const float4* c2r = (const float4*)(c2s + j * 16);
            const float4 q0 = c2r[0], q1 = c2r[1], q2 = c2r[2], q3 = c2r[3];
            float bj[4];
#pragma unroll
            for (int t = 0; t < 4; ++t) bj[t] = dot16(q0, q1, q2, q3, xr[t]);
#pragma unroll 4
            for (int i = 0; i < 16; ++i) {
                const float4* row = (const float4*)(c3s + (j * 16 + i) * 16);
                const float4 r0 = row[0], r1 = row[1], r2 = row[2], r3 = row[3];
#pragma unroll
                for (int t = 0; t < 4; ++t) {
                    const float s = dot16(r0, r1, r2, r3, xr[t]);
                    bj[t] = fmaf(xr[t][i], s, bj[t]);
                }
            }
            const float c1v = c1s[j];
#pragma unroll
            for (int t = 0; t < 4; ++t) {
                const float xj = xs[j * 256 + t * 64 + lane];  // LDS, not dyn reg idx
                fmp[t] = fmaf(bj[t] + c1v, xj, fmp[t]);
            }
        }
        __syncthreads();  // all xs reads done before alias overwrite

        float* red = xs;  // alias: red[wave][slot_local]
#pragma unroll
        for (int t = 0; t < 4; ++t) red[wave * 256 + t * 64 + lane] = fmp[t];
        __syncthreads();
        {
            const int slot = base + tid;
            if (slot < cnt) {
                const float s = red[tid] + red[256 + tid] + red[512 + tid] + red[768 + tid];
                outg[(size_t)list[slot] * 512 + OUTBASE + c * CM + m] = s;
            }
        }
        __syncthreads();  // before next sweep's xs reload
    }
}

extern "C" void kernel_launch(void* const* d_in, const int* in_sizes, int n_in,
                              void* d_out, int out_size, void* d_ws, size_t ws_size,
                              hipStream_t stream) {
    const float* x = (const float*)d_in[0];
    const float* y = (const float*)d_in[1];
    const float* U3_0 = (const float*)d_in[2];
    const float* U2_0 = (const float*)d_in[3];
    const float* U1_0 = (const float*)d_in[4];
    const float* W3_0 = (const float*)d_in[5];
    const float* W2_0 = (const float*)d_in[6];
    const float* W1_0 = (const float*)d_in[7];
    const float* U3_1 = (const float*)d_in[8];
    const float* U2_1 = (const float*)d_in[9];
    const float* U1_1 = (const float*)d_in[10];
    const float* W3_1 = (const float*)d_in[11];
    const float* W2_1 = (const float*)d_in[12];
    const float* W1_1 = (const float*)d_in[13];
    float* out = (float*)d_out;
    int* ws = (int*)d_ws;

    compact_kernel<<<1, 256, 0, stream>>>(y, ws);

    // part1 (1o): M=3, col = 128 + c*3 + m
    sc_main<33, 5, 3, 128><<<dim3(CN, EN, 3), 256, 0, stream>>>(
        x, U3_1, U2_1, U1_1, W3_1, W2_1, W1_1, ws, out);
    // part0 (0e): M=1, col = c
    sc_main<23, 4, 1, 0><<<dim3(CN, EN, 1), 256, 0, stream>>>(
        x, U3_0, U2_0, U1_0, W3_0, W2_0, W1_0, ws, out);
}

// Round 5
// 572.008 us; speedup vs baseline: 1.1974x; 1.1938x over previous
//
#include <hip/hip_runtime.h>
#include <stdint.h>

// SymmetricContraction (MACE) on MI355X, fp32 I/O.
// R5: three-phase dataflow.
//  A) build combined per-(e,c,m) tables ONCE into d_ws:
//       tab3[e,c,mhat][j,i,l] = sum_k U3[m,i,j,l,k] W3[e,k,c]   (84 MB)
//       tab2[e,c,mhat][j,l]   = sum_k U2[m,j,l,k]   W2[e,k,c]   (5 MB)
//       tab1[e,c,mhat][j]     =       U1[m,j]       W1[e,c]     (0.3 MB)
//     (R4 rebuilt these per block -> 2 GB logical U3 refetch, 560 MB HBM)
//  B) sc_main (R4's proven inner loop): load 16KB table slice, stage x in LDS,
//     NT=4 nodes/lane, 4-way j-split, write out_ws[col][p] with p = position
//     in element-sorted node order -> contiguous stores, no amplification.
//     (R4 scattered dword stores -> 87x write amplification, 349 MB)
//  C) finalize: LDS-tiled transpose out_ws[col][p] -> out[b][col], full lines.
// mhat: 0 = part0(m=0); 1..3 = part1(m=0..2).

#define BN 2048
#define CN 128
#define EN 10

// float-offsets inside d_ws (ints live in the first 4096 floats' space)
#define OFF_TAB3 4096
#define OFF_TAB2 (OFF_TAB3 + 10 * 128 * 4 * 4096)
#define OFF_TAB1 (OFF_TAB2 + 10 * 128 * 4 * 256)
#define OFF_OUT  (OFF_TAB1 + 10 * 128 * 4 * 16)
// end = OFF_OUT + 512*2048 = 23,416,832 floats (~94 MB of ws)

// ints: wsI[0..9]=counts, wsI[16..25]=starts, wsI[32..32+2047]=plist (b per p)
__global__ void compact_kernel(const float* __restrict__ yg, int* __restrict__ wsI) {
    __shared__ int cnt_s[EN], cur_s[EN], start_s[EN];
    const int tid = threadIdx.x;
    if (tid < EN) cnt_s[tid] = 0;
    __syncthreads();
    for (int b = tid; b < BN; b += 256) {
#pragma unroll
        for (int e = 0; e < EN; ++e) {
            if (yg[b * EN + e] > 0.5f) { atomicAdd(&cnt_s[e], 1); break; }
        }
    }
    __syncthreads();
    if (tid == 0) {
        int run = 0;
        for (int e = 0; e < EN; ++e) { start_s[e] = run; run += cnt_s[e]; }
    }
    __syncthreads();
    if (tid < EN) {
        cur_s[tid] = start_s[tid];
        wsI[tid] = cnt_s[tid];
        wsI[16 + tid] = start_s[tid];
    }
    __syncthreads();
    for (int b = tid; b < BN; b += 256) {
#pragma unroll
        for (int e = 0; e < EN; ++e) {
            if (yg[b * EN + e] > 0.5f) {
                int p = atomicAdd(&cur_s[e], 1);
                wsI[32 + p] = b;
                break;
            }
        }
    }
}

// ---- Phase A: tab3. grid (16 chunks, Mloc, E), block 128 (thread <-> c).
// U3 row address is wave-uniform -> SMEM loads; W3 column in VGPRs.
// Stores staged through LDS transpose -> full-line coalesced writes.
template <int K3>
__global__ __launch_bounds__(128) void build3(
    const float* __restrict__ U3, const float* __restrict__ W3,
    float* __restrict__ fw, int mhat_off)
{
    const int c = threadIdx.x;
    const int chunk = blockIdx.x;   // 16 chunks x 256 rows
    const int mloc = blockIdx.y;
    const int e = blockIdx.z;
    const int mhat = mhat_off + mloc;
    __shared__ float trans[128 * 17];

    float w[K3];
#pragma unroll
    for (int k = 0; k < K3; ++k) w[k] = W3[(e * K3 + k) * CN + c];

    const float* U3m = U3 + (size_t)mloc * 4096 * K3;
    float* tab3 = fw + OFF_TAB3;
    const int rbase0 = chunk * 256;

    for (int batch = 0; batch < 16; ++batch) {
        const int rbase = rbase0 + batch * 16;
#pragma unroll
        for (int rr = 0; rr < 16; ++rr) {
            const int row = rbase + rr;       // LDS order [j][i][l]
            const int l = row & 15, i = (row >> 4) & 15, j = row >> 8;
            const float* up = U3m + (size_t)((i * 16 + j) * 16 + l) * K3;  // uniform
            float a = 0.f;
#pragma unroll
            for (int k = 0; k < K3; ++k) a = fmaf(up[k], w[k], a);
            trans[c * 17 + rr] = a;           // stride-17: conflict-free
        }
        __syncthreads();
#pragma unroll
        for (int s = 0; s < 4; ++s) {
            const int cc = s * 32 + (threadIdx.x >> 2);
            const int q = threadIdx.x & 3;
            float4 v = make_float4(trans[cc * 17 + q * 4], trans[cc * 17 + q * 4 + 1],
                                   trans[cc * 17 + q * 4 + 2], trans[cc * 17 + q * 4 + 3]);
            float4* dst = (float4*)(tab3 + ((size_t)((e * CN + cc) * 4 + mhat)) * 4096 + rbase);
            dst[q] = v;
        }
        __syncthreads();
    }
}

// ---- Phase A: tab2 + tab1. grid (E, Mloc), block 256 (thread <-> jl row).
template <int K2>
__global__ __launch_bounds__(256) void build21(
    const float* __restrict__ U2, const float* __restrict__ W2,
    const float* __restrict__ U1, const float* __restrict__ W1,
    float* __restrict__ fw, int mhat_off)
{
    const int e = blockIdx.x;
    const int mloc = blockIdx.y;
    const int mhat = mhat_off + mloc;
    const int jl = threadIdx.x;   // 0..255
    float u2[K2];
#pragma unroll
    for (int k = 0; k < K2; ++k) u2[k] = U2[((size_t)mloc * 256 + jl) * K2 + k];
    float* tab2 = fw + OFF_TAB2;
#pragma unroll 4
    for (int c = 0; c < CN; ++c) {
        float a = 0.f;
#pragma unroll
        for (int k = 0; k < K2; ++k) a = fmaf(u2[k], W2[(e * K2 + k) * CN + c], a);  // uniform W2
        tab2[((size_t)((e * CN + c) * 4 + mhat)) * 256 + jl] = a;   // coalesced
    }
    float* tab1 = fw + OFF_TAB1;
    for (int idx = threadIdx.x; idx < CN * 16; idx += 256) {
        const int c = idx >> 4, j = idx & 15;
        tab1[((size_t)((e * CN + c) * 4 + mhat)) * 16 + j] = U1[mloc * 16 + j] * W1[e * CN + c];
    }
}

__device__ __forceinline__ float dot16(const float4 r0, const float4 r1,
                                       const float4 r2, const float4 r3,
                                       const float* x) {
    float a = r0.x * x[0];
    a = fmaf(r0.y, x[1], a);
    a = fmaf(r0.z, x[2], a);
    a = fmaf(r0.w, x[3], a);
    a = fmaf(r1.x, x[4], a);
    a = fmaf(r1.y, x[5], a);
    a = fmaf(r1.z, x[6], a);
    a = fmaf(r1.w, x[7], a);
    a = fmaf(r2.x, x[8], a);
    a = fmaf(r2.y, x[9], a);
    a = fmaf(r2.z, x[10], a);
    a = fmaf(r2.w, x[11], a);
    a = fmaf(r3.x, x[12], a);
    a = fmaf(r3.y, x[13], a);
    a = fmaf(r3.z, x[14], a);
    a = fmaf(r3.w, x[15], a);
    return a;
}

// ---- Phase B: grid (c, e, mloc). Inner loop identical to R4 (verified).
__global__ __launch_bounds__(256, 4) void sc_main(
    const float* __restrict__ xg, const float* __restrict__ fw,
    const int* __restrict__ wsI, int mhat_off)
{
    const int c = blockIdx.x;
    const int e = blockIdx.y;
    const int mhat = mhat_off + blockIdx.z;
    const int col = (mhat == 0) ? c : (CN + c * 3 + (mhat - 1));
    const int tid = threadIdx.x;
    const int lane = tid & 63;
    const int wave = tid >> 6;

    __shared__ float c3s[4096];     // [j][i][l]
    __shared__ float c2s[256];      // [j][l]
    __shared__ float c1s[16];
    __shared__ float xs[16 * 256];  // [i][slot]; first 1024 aliased as red[4][256]

    const size_t tb = (size_t)((e * CN + c) * 4 + mhat);
    {
        const float4* s3 = (const float4*)(fw + OFF_TAB3 + tb * 4096);
        float4* d3 = (float4*)c3s;
        for (int i = tid; i < 1024; i += 256) d3[i] = s3[i];
        const float4* s2 = (const float4*)(fw + OFF_TAB2 + tb * 256);
        if (tid < 64) ((float4*)c2s)[tid] = s2[tid];
        if (tid < 16) c1s[tid] = fw[OFF_TAB1 + tb * 16 + tid];
    }
    __syncthreads();

    const int cnt = wsI[e];
    const int start = wsI[16 + e];
    const int* list = wsI + 32 + start;
    float* outws = (float*)(fw + OFF_OUT);

    for (int base = 0; base < cnt; base += 256) {
        {
            const int slot = base + tid;
            const int n = (slot < cnt) ? list[slot] : list[cnt - 1];
            const float4* xp = (const float4*)(xg + ((size_t)n * CN + c) * 16);
            const float4 a0 = xp[0], a1 = xp[1], a2 = xp[2], a3 = xp[3];
            float v[16];
            v[0] = a0.x; v[1] = a0.y; v[2] = a0.z; v[3] = a0.w;
            v[4] = a1.x; v[5] = a1.y; v[6] = a1.z; v[7] = a1.w;
            v[8] = a2.x; v[9] = a2.y; v[10] = a2.z; v[11] = a2.w;
            v[12] = a3.x; v[13] = a3.y; v[14] = a3.z; v[15] = a3.w;
#pragma unroll
            for (int i = 0; i < 16; ++i) xs[i * 256 + tid] = v[i];
        }
        __syncthreads();

        float xr[4][16];
#pragma unroll
        for (int t = 0; t < 4; ++t)
#pragma unroll
            for (int i = 0; i < 16; ++i) xr[t][i] = xs[i * 256 + t * 64 + lane];

        float fmp[4] = {0.f, 0.f, 0.f, 0.f};
#pragma unroll 1
        for (int jj = 0; jj < 4; ++jj) {
            const int j = wave * 4 + jj;
            const float4* c2r = (const float4*)(c2s + j * 16);
            const float4 q0 = c2r[0], q1 = c2r[1], q2 = c2r[2], q3 = c2r[3];
            float bj[4];
#pragma unroll
            for (int t = 0; t < 4; ++t) bj[t] = dot16(q0, q1, q2, q3, xr[t]);
#pragma unroll 4
            for (int i = 0; i < 16; ++i) {
                const float4* row = (const float4*)(c3s + (j * 16 + i) * 16);
                const float4 r0 = row[0], r1 = row[1], r2 = row[2], r3 = row[3];
#pragma unroll
                for (int t = 0; t < 4; ++t) {
                    const float s = dot16(r0, r1, r2, r3, xr[t]);
                    bj[t] = fmaf(xr[t][i], s, bj[t]);
                }
            }
            const float c1v = c1s[j];
#pragma unroll
            for (int t = 0; t < 4; ++t) {
                const float xj = xs[j * 256 + t * 64 + lane];
                fmp[t] = fmaf(bj[t] + c1v, xj, fmp[t]);
            }
        }
        __syncthreads();

        float* red = xs;
#pragma unroll
        for (int t = 0; t < 4; ++t) red[wave * 256 + t * 64 + lane] = fmp[t];
        __syncthreads();
        {
            const int slot = base + tid;
            if (slot < cnt) {
                const float s = red[tid] + red[256 + tid] + red[512 + tid] + red[768 + tid];
                outws[(size_t)col * BN + start + slot] = s;   // contiguous per block
            }
        }
        __syncthreads();
    }
}

// ---- Finalize: out_ws[col][p] -> out[b][col], LDS tile, full-line traffic.
__global__ __launch_bounds__(256) void finalize(
    const float* __restrict__ fw, const int* __restrict__ wsI,
    float* __restrict__ outg)
{
    const int p0 = blockIdx.x * 64;
    const int tid = threadIdx.x;
    __shared__ float buf[64 * 129];
    const float* outws = fw + OFF_OUT;
    for (int c0 = 0; c0 < 512; c0 += 128) {
        for (int idx = tid; idx < 64 * 128; idx += 256) {
            const int pp = idx & 63, cc = idx >> 6;      // lanes: consecutive p -> coalesced
            buf[pp * 129 + cc] = outws[(size_t)(c0 + cc) * BN + p0 + pp];
        }
        __syncthreads();
        for (int idx = tid; idx < 64 * 128; idx += 256) {
            const int cc = idx & 127, pp = idx >> 7;     // lanes: consecutive col -> full lines
            outg[(size_t)wsI[32 + p0 + pp] * 512 + c0 + cc] = buf[pp * 129 + cc];
        }
        __syncthreads();
    }
}

extern "C" void kernel_launch(void* const* d_in, const int* in_sizes, int n_in,
                              void* d_out, int out_size, void* d_ws, size_t ws_size,
                              hipStream_t stream) {
    const float* x = (const float*)d_in[0];
    const float* y = (const float*)d_in[1];
    const float* U3_0 = (const float*)d_in[2];
    const float* U2_0 = (const float*)d_in[3];
    const float* U1_0 = (const float*)d_in[4];
    const float* W3_0 = (const float*)d_in[5];
    const float* W2_0 = (const float*)d_in[6];
    const float* W1_0 = (const float*)d_in[7];
    const float* U3_1 = (const float*)d_in[8];
    const float* U2_1 = (const float*)d_in[9];
    const float* U1_1 = (const float*)d_in[10];
    const float* W3_1 = (const float*)d_in[11];
    const float* W2_1 = (const float*)d_in[12];
    const float* W1_1 = (const float*)d_in[13];
    float* out = (float*)d_out;
    float* fw = (float*)d_ws;
    int* wsI = (int*)d_ws;

    compact_kernel<<<1, 256, 0, stream>>>(y, wsI);

    build3<23><<<dim3(16, 1, EN), 128, 0, stream>>>(U3_0, W3_0, fw, 0);
    build3<33><<<dim3(16, 3, EN), 128, 0, stream>>>(U3_1, W3_1, fw, 1);
    build21<4><<<dim3(EN, 1), 256, 0, stream>>>(U2_0, W2_0, U1_0, W1_0, fw, 0);
    build21<5><<<dim3(EN, 3), 256, 0, stream>>>(U2_1, W2_1, U1_1, W1_1, fw, 1);

    sc_main<<<dim3(CN, EN, 3), 256, 0, stream>>>(x, fw, wsI, 1);  // part1
    sc_main<<<dim3(CN, EN, 1), 256, 0, stream>>>(x, fw, wsI, 0);  // part0

    finalize<<<32, 256, 0, stream>>>(fw, wsI, out);
}